// Round 6
// baseline (25.542 us; speedup 1.0000x reference)
//
#include <hip/hip_runtime.h>
#include <math.h>

// Barrier-free version: one wave per row, 4 waves per block. No LDS, no
// __syncthreads, no atomics on any path. Fast path (cyclic table, verified
// on-device from L2 each call): s_final = (sum of row ids) % N. Fallback
// (any group table): per-wave order-preserving shuffle-doubling composition.

#define BLK 256
#define WAVES_PER_BLK 4

__global__ __launch_bounds__(BLK) void a5_r6_kernel(
    const int* __restrict__ ids, const int* __restrict__ mul,
    const float* __restrict__ neg_fill, float* __restrict__ out,
    int T, int N, int B)
{
    const int tid  = threadIdx.x;
    const int lane = tid & 63;
    const int wv   = tid >> 6;
    const int row  = blockIdx.x * WAVES_PER_BLK + wv;
    if (row >= B) return;

    const int NN = N * N;
    const int* rowp = ids + (size_t)row * (size_t)T;
    const int4* v = reinterpret_cast<const int4*>(rowp);
    const int nv = T >> 2;

    int sum = 0;
    int myBad = 0;

    if (nv == 16 * 64) {
        // T = 4096: 16 wave-stride int4 loads per lane, issued up front.
        int4 g[16];
        #pragma unroll
        for (int k = 0; k < 16; ++k) g[k] = v[lane + (k << 6)];

        // Verify table from L2 (lane-strided int4, broadcast across waves)
        // while the HBM row loads are in flight.
        const int4* mv = reinterpret_cast<const int4*>(mul);
        const int nmv = NN >> 2;
        for (int j = lane; j < nmv; j += 64) {
            int4 m = mv[j];
            int base = j << 2;
            #pragma unroll
            for (int q = 0; q < 4; ++q) {
                int idx = base + q;
                int gg = idx / N;
                int ss = idx - gg * N;
                int e = gg + ss; if (e >= N) e -= N;
                int val = (q == 0) ? m.x : (q == 1) ? m.y : (q == 2) ? m.z : m.w;
                myBad |= (val != e);
            }
        }
        for (int idx = (nmv << 2) + lane; idx < NN; idx += 64) {  // tail
            int gg = idx / N;
            int ss = idx - gg * N;
            int e = gg + ss; if (e >= N) e -= N;
            myBad |= (mul[idx] != e);
        }

        #pragma unroll
        for (int k = 0; k < 16; ++k)
            sum += (g[k].x + g[k].y) + (g[k].z + g[k].w);
    } else {
        // Generic shape path.
        for (int i = lane; i < nv; i += 64) {
            int4 x = v[i];
            sum += (x.x + x.y) + (x.z + x.w);
        }
        for (int k = ((T >> 2) << 2) + lane; k < T; k += 64) sum += rowp[k];
        for (int idx = lane; idx < NN; idx += 64) {
            int gg = idx / N;
            int ss = idx - gg * N;
            int e = gg + ss; if (e >= N) e -= N;
            myBad |= (mul[idx] != e);
        }
    }

    const bool bad = __any(myBad);   // wave-uniform verdict, no LDS needed
    int sfin;

    if (!bad) {
        // ---- Fast path: butterfly sum, all lanes end with the total ------
        #pragma unroll
        for (int off = 1; off < 64; off <<= 1) sum += __shfl_xor(sum, off);
        sfin = sum % N;                         // s0 = 0 (identity)
    } else {
        // ---- Fallback: order-preserving shuffle-doubling composition -----
        // Lane l composes its contiguous chunk serially (later-on-left).
        const int C = (T + 63) >> 6;            // chunk per lane
        int p = -1;
        for (int k = lane * C; k < lane * C + C && k < T; ++k) {
            int gk = rowp[k];
            p = (p < 0) ? gk : mul[gk * N + p];
        }
        if (p < 0) p = 0;                       // empty chunk -> identity
        // Doubling combine: at step k, partner chunk is adjacent; lane with
        // bit k clear holds the EARLIER segment.
        #pragma unroll
        for (int k = 1; k < 64; k <<= 1) {
            int q = __shfl_xor(p, k);
            p = (lane & k) ? mul[p * N + q]     // mine later:  p ∘ q
                           : mul[q * N + p];    // mine earlier: q ∘ p
        }
        sfin = mul[p * N + 0];                  // apply composed map to s0=0
    }

    // ---- Output: lanes < N write the row ---------------------------------
    const float nf = neg_fill[0];
    for (int col = lane; col < N; col += 64)
        out[(size_t)row * N + col] = (col == sfin) ? 0.0f : nf;
}

extern "C" void kernel_launch(void* const* d_in, const int* in_sizes, int n_in,
                              void* d_out, int out_size, void* d_ws, size_t ws_size,
                              hipStream_t stream) {
    const int* ids = (const int*)d_in[0];
    const int* mul = (const int*)d_in[1];
    const float* neg = (const float*)d_in[2];
    float* out = (float*)d_out;

    const int NN = in_sizes[1];
    int N = (int)(sqrt((double)NN) + 0.5);
    if (N * N != NN) N = 60;
    const int B = out_size / N;
    const int T = in_sizes[0] / B;
    const int nblk = (B + WAVES_PER_BLK - 1) / WAVES_PER_BLK;

    a5_r6_kernel<<<dim3(nblk), dim3(BLK), 0, stream>>>(ids, mul, neg, out, T, N, B);
}

// Round 7
// 20.879 us; speedup vs baseline: 1.2233x; 1.2233x over previous
//
#include <hip/hip_runtime.h>
#include <math.h>

// Best-merged version (R7): one row per block, loads-first, register-resident
// table verification (all loads issued before any use -> single vmcnt drain),
// two barriers on the hot path. Fast path (cyclic table): s_final =
// (sum ids) % N. Fallback (any group table): order-preserving LDS-table
// composition, staged only on the cold branch.

#define BLK 256

__global__ __launch_bounds__(BLK) void a5_r7_kernel(
    const int* __restrict__ ids, const int* __restrict__ mul,
    const float* __restrict__ neg_fill, float* __restrict__ out,
    int T, int N)
{
    __shared__ int sp[BLK];
    __shared__ int mul_lds[64 * 64];   // touched only on the fallback path

    const int tid = threadIdx.x;
    const int row = blockIdx.x;
    const int NN = N * N;
    const int* rowp = ids + (size_t)row * (size_t)T;
    const int4* v = reinterpret_cast<const int4*>(rowp);
    const int nv = T >> 2;

    int sum = 0, myBad = 0;

    if (nv == 4 * BLK && (NN & 3) == 0) {
        // T = 4096 fast case: 4 row int4 loads + up to 4 table int4 loads,
        // ALL issued before any consumption.
        int4 a0 = v[tid];
        int4 a1 = v[tid + BLK];
        int4 a2 = v[tid + 2 * BLK];
        int4 a3 = v[tid + 3 * BLK];

        const int4* mv = reinterpret_cast<const int4*>(mul);
        const int nmv = NN >> 2;                  // 900 for N=60
        int4 m0 = {0,0,0,0}, m1 = {0,0,0,0}, m2 = {0,0,0,0}, m3 = {0,0,0,0};
        if (tid           < nmv) m0 = mv[tid];
        if (tid + BLK     < nmv) m1 = mv[tid + BLK];
        if (tid + 2 * BLK < nmv) m2 = mv[tid + 2 * BLK];
        if (tid + 3 * BLK < nmv) m3 = mv[tid + 3 * BLK];

        // Verify from registers.
        #pragma unroll
        for (int c = 0; c < 4; ++c) {
            int j = tid + c * BLK;
            if (j < nmv) {
                int4 m = (c == 0) ? m0 : (c == 1) ? m1 : (c == 2) ? m2 : m3;
                int base = j << 2;
                #pragma unroll
                for (int q = 0; q < 4; ++q) {
                    int idx = base + q;
                    int gg = idx / N;
                    int ss = idx - gg * N;
                    int e = gg + ss; if (e >= N) e -= N;
                    int val = (q == 0) ? m.x : (q == 1) ? m.y : (q == 2) ? m.z : m.w;
                    myBad |= (val != e);
                }
            }
        }

        sum = ((a0.x + a0.y) + (a0.z + a0.w)) + ((a1.x + a1.y) + (a1.z + a1.w))
            + ((a2.x + a2.y) + (a2.z + a2.w)) + ((a3.x + a3.y) + (a3.z + a3.w));
    } else {
        // Generic shape path.
        for (int i = tid; i < nv; i += BLK) {
            int4 x = v[i];
            sum += (x.x + x.y) + (x.z + x.w);
        }
        for (int k = ((T >> 2) << 2) + tid; k < T; k += BLK) sum += rowp[k];
        for (int idx = tid; idx < NN; idx += BLK) {
            int gg = idx / N;
            int ss = idx - gg * N;
            int e = gg + ss; if (e >= N) e -= N;
            myBad |= (mul[idx] != e);
        }
    }

    // Wave reduce: sum via shuffles, badness via __any.
    #pragma unroll
    for (int off = 32; off > 0; off >>= 1) sum += __shfl_down(sum, off);
    const int wbad = __any(myBad) ? 1 : 0;
    const int wv = tid >> 6;
    if ((tid & 63) == 0) { sp[wv] = sum; sp[8 + wv] = wbad; }
    __syncthreads();                                    // barrier 1

    if (tid == 0) {
        int s = 0, bad = 0;
        #pragma unroll
        for (int w = 0; w < BLK / 64; ++w) { s += sp[w]; bad |= sp[8 + w]; }
        sp[16] = bad;
        sp[17] = s % N;                  // s0 = 0 (identity): valid iff !bad
    }
    __syncthreads();                                    // barrier 2

    int sfin;
    if (!sp[16]) {
        sfin = sp[17];
    } else {
        // ---- Fallback: order-preserving composition via LDS table --------
        for (int i = tid; i < NN; i += BLK) mul_lds[i] = mul[i];
        __syncthreads();

        const int chunk = (T + BLK - 1) / BLK;
        int p = -1;
        for (int k = tid * chunk; k < tid * chunk + chunk && k < T; ++k) {
            int gk = rowp[k];
            p = (p < 0) ? gk : mul_lds[gk * N + p];
        }
        if (p < 0) p = 0;
        sp[tid] = p;

        int cnt = BLK;
        while (cnt > 1) {
            __syncthreads();
            const int half = cnt >> 1;
            int tv = 0;
            if (tid < half) {
                int a = sp[2 * tid];          // earlier
                int b = sp[2 * tid + 1];      // later
                tv = mul_lds[b * N + a];
            }
            __syncthreads();
            if (tid < half) sp[tid] = tv;
            cnt = half;
        }
        __syncthreads();
        if (tid == 0) sp[0] = mul_lds[sp[0] * N + 0];   // apply to s0 = 0
        __syncthreads();
        sfin = sp[0];
    }

    const float nf = neg_fill[0];
    if (tid < N)
        out[(size_t)row * N + tid] = (tid == sfin) ? 0.0f : nf;
}

extern "C" void kernel_launch(void* const* d_in, const int* in_sizes, int n_in,
                              void* d_out, int out_size, void* d_ws, size_t ws_size,
                              hipStream_t stream) {
    const int* ids = (const int*)d_in[0];
    const int* mul = (const int*)d_in[1];
    const float* neg = (const float*)d_in[2];
    float* out = (float*)d_out;

    const int NN = in_sizes[1];
    int N = (int)(sqrt((double)NN) + 0.5);
    if (N * N != NN) N = 60;
    const int B = out_size / N;
    const int T = in_sizes[0] / B;

    a5_r7_kernel<<<dim3(B), dim3(BLK), 0, stream>>>(ids, mul, neg, out, T, N);
}